// Round 4
// baseline (311.076 us; speedup 1.0000x reference)
//
#include <hip/hip_runtime.h>
#include <math.h>

#define Nn 6144
#define Cc 128
#define NHD 2
#define MAXDEG 1024

// ---------------- warp/block reduction helpers ----------------
__device__ __forceinline__ float wave_red_sum(float v) {
#pragma unroll
  for (int o = 32; o; o >>= 1) v += __shfl_xor(v, o);
  return v;
}

// reduce (a,b) across a 256-thread block. red = float[8] LDS scratch.
template <bool IS_MAX>
__device__ __forceinline__ void block_red2(float& a, float& b, float* red) {
#pragma unroll
  for (int o = 32; o; o >>= 1) {
    float ta = __shfl_xor(a, o), tb = __shfl_xor(b, o);
    if (IS_MAX) { a = fmaxf(a, ta); b = fmaxf(b, tb); }
    else        { a += ta;          b += tb;          }
  }
  int wid = threadIdx.x >> 6;
  __syncthreads();  // protect red from previous use
  if ((threadIdx.x & 63) == 0) { red[wid] = a; red[4 + wid] = b; }
  __syncthreads();
  if (IS_MAX) {
    a = fmaxf(fmaxf(red[0], red[1]), fmaxf(red[2], red[3]));
    b = fmaxf(fmaxf(red[4], red[5]), fmaxf(red[6], red[7]));
  } else {
    a = red[0] + red[1] + red[2] + red[3];
    b = red[4] + red[5] + red[6] + red[7];
  }
}

// ---------------- kernel 1: x_norm = LN(x; g1,b1) ----------------
__global__ __launch_bounds__(256) void k_ln(const float* __restrict__ x,
                                            const float* __restrict__ g,
                                            const float* __restrict__ b,
                                            float* __restrict__ xn) {
  int wid = threadIdx.x >> 6, lane = threadIdx.x & 63;
  int row = blockIdx.x * 4 + wid;
  float2 v = ((const float2*)(x + (size_t)row * Cc))[lane];
  float s = v.x + v.y;
#pragma unroll
  for (int o = 32; o; o >>= 1) s += __shfl_xor(s, o);
  float mean = s * (1.0f / Cc);
  float dx = v.x - mean, dy = v.y - mean;
  float q = dx * dx + dy * dy;
#pragma unroll
  for (int o = 32; o; o >>= 1) q += __shfl_xor(q, o);
  float rstd = rsqrtf(q * (1.0f / Cc) + 1e-5f);
  int c = lane * 2;
  float* o = xn + (size_t)row * Cc;
  o[c]     = dx * rstd * g[c] + b[c];
  o[c + 1] = dy * rstd * g[c + 1] + b[c + 1];
}

// ---------------- tiled fp32 GEMM (h = x_norm @ ff0^T, per head) -----------
// out[head][r][c] = sum_k A[r][k] * B[head][c][k]
__global__ __launch_bounds__(256) void k_gemm_ff0(const float* __restrict__ A,
                                                  const float* __restrict__ Bw,
                                                  float* __restrict__ out) {
  __shared__ float As[64][68];   // [k][r], padded (2-way conflict max: free)
  __shared__ float Bs[64][132];  // [k][c], padded
  const int t = threadIdx.x;
  const int head = blockIdx.y;
  const int row0 = blockIdx.x * 64;
  const float* Bh = Bw + (size_t)head * Cc * Cc;
  const int tr = t & 15, tc = t >> 4;
  const int r0 = tr * 4, c0 = tc * 8;
  float acc[4][8];
#pragma unroll
  for (int i = 0; i < 4; i++)
#pragma unroll
    for (int j = 0; j < 8; j++) acc[i][j] = 0.f;

  for (int kt = 0; kt < Cc; kt += 64) {
    __syncthreads();
    for (int i = t; i < 1024; i += 256) {
      int rr = i >> 4, k4 = i & 15;
      float4 v = *(const float4*)(A + (size_t)(row0 + rr) * Cc + kt + k4 * 4);
      As[k4 * 4 + 0][rr] = v.x; As[k4 * 4 + 1][rr] = v.y;
      As[k4 * 4 + 2][rr] = v.z; As[k4 * 4 + 3][rr] = v.w;
    }
    for (int i = t; i < 2048; i += 256) {
      int cc2 = i >> 4, k4 = i & 15;
      float4 v = *(const float4*)(Bh + (size_t)cc2 * Cc + kt + k4 * 4);
      Bs[k4 * 4 + 0][cc2] = v.x; Bs[k4 * 4 + 1][cc2] = v.y;
      Bs[k4 * 4 + 2][cc2] = v.z; Bs[k4 * 4 + 3][cc2] = v.w;
    }
    __syncthreads();
#pragma unroll
    for (int k = 0; k < 64; k++) {
      float4 a  = *(const float4*)&As[k][r0];
      float4 b0 = *(const float4*)&Bs[k][c0];
      float4 b1 = *(const float4*)&Bs[k][c0 + 4];
      float av[4] = {a.x, a.y, a.z, a.w};
      float bv[8] = {b0.x, b0.y, b0.z, b0.w, b1.x, b1.y, b1.z, b1.w};
#pragma unroll
      for (int i = 0; i < 4; i++)
#pragma unroll
        for (int j = 0; j < 8; j++) acc[i][j] = fmaf(av[i], bv[j], acc[i][j]);
    }
  }
#pragma unroll
  for (int i = 0; i < 4; i++) {
    float* op = out + ((size_t)head * Nn + row0 + r0 + i) * Cc + c0;
    *(float4*)(op)     = make_float4(acc[i][0], acc[i][1], acc[i][2], acc[i][3]);
    *(float4*)(op + 4) = make_float4(acc[i][4], acc[i][5], acc[i][6], acc[i][7]);
  }
}

// ---------------- fused FF1 GEMM + head-combine -----------------------------
// out[r][c] = sum_head elu( sum_k attn[head][r][k] * ff1[head][c][k] ) * 0.5
// One block owns a 64x128 output tile and loops both heads internally,
// eliminating the outh workspace round-trip and the k_combine kernel.
__global__ __launch_bounds__(256) void k_gemm_ff1(const float* __restrict__ A,
                                                  const float* __restrict__ Bw,
                                                  float* __restrict__ out) {
  __shared__ float As[64][68];
  __shared__ float Bs[64][132];
  const int t = threadIdx.x;
  const int row0 = blockIdx.x * 64;
  const int tr = t & 15, tc = t >> 4;
  const int r0 = tr * 4, c0 = tc * 8;
  float sum[4][8];
#pragma unroll
  for (int i = 0; i < 4; i++)
#pragma unroll
    for (int j = 0; j < 8; j++) sum[i][j] = 0.f;

  for (int head = 0; head < NHD; head++) {
    const float* Ah = A + (size_t)head * Nn * Cc;
    const float* Bh = Bw + (size_t)head * Cc * Cc;
    float acc[4][8];
#pragma unroll
    for (int i = 0; i < 4; i++)
#pragma unroll
      for (int j = 0; j < 8; j++) acc[i][j] = 0.f;

    for (int kt = 0; kt < Cc; kt += 64) {
      __syncthreads();  // also protects As/Bs across the head loop
      for (int i = t; i < 1024; i += 256) {
        int rr = i >> 4, k4 = i & 15;
        float4 v = *(const float4*)(Ah + (size_t)(row0 + rr) * Cc + kt + k4 * 4);
        As[k4 * 4 + 0][rr] = v.x; As[k4 * 4 + 1][rr] = v.y;
        As[k4 * 4 + 2][rr] = v.z; As[k4 * 4 + 3][rr] = v.w;
      }
      for (int i = t; i < 2048; i += 256) {
        int cc2 = i >> 4, k4 = i & 15;
        float4 v = *(const float4*)(Bh + (size_t)cc2 * Cc + kt + k4 * 4);
        Bs[k4 * 4 + 0][cc2] = v.x; Bs[k4 * 4 + 1][cc2] = v.y;
        Bs[k4 * 4 + 2][cc2] = v.z; Bs[k4 * 4 + 3][cc2] = v.w;
      }
      __syncthreads();
#pragma unroll
      for (int k = 0; k < 64; k++) {
        float4 a  = *(const float4*)&As[k][r0];
        float4 b0 = *(const float4*)&Bs[k][c0];
        float4 b1 = *(const float4*)&Bs[k][c0 + 4];
        float av[4] = {a.x, a.y, a.z, a.w};
        float bv[8] = {b0.x, b0.y, b0.z, b0.w, b1.x, b1.y, b1.z, b1.w};
#pragma unroll
        for (int i = 0; i < 4; i++)
#pragma unroll
          for (int j = 0; j < 8; j++) acc[i][j] = fmaf(av[i], bv[j], acc[i][j]);
      }
    }
    // elu + 0.5 scale, accumulate across heads
#pragma unroll
    for (int i = 0; i < 4; i++)
#pragma unroll
      for (int j = 0; j < 8; j++) {
        float v = acc[i][j];
        v = (v > 0.f) ? v : (expf(v) - 1.f);
        sum[i][j] = fmaf(v, 0.5f, sum[i][j]);
      }
  }
#pragma unroll
  for (int i = 0; i < 4; i++) {
    float* op = out + (size_t)(row0 + r0 + i) * Cc + c0;
    *(float4*)(op)     = make_float4(sum[i][0], sum[i][1], sum[i][2], sum[i][3]);
    *(float4*)(op + 4) = make_float4(sum[i][4], sum[i][5], sum[i][6], sum[i][7]);
  }
}

// ---------------- kernel 2b: s_src/s_dst = h . attn_w halves ----------------
__global__ __launch_bounds__(256) void k_attn_s(const float* __restrict__ h,
                                                const float* __restrict__ aw,
                                                float* __restrict__ ssrc,
                                                float* __restrict__ sdst) {
  int wid = threadIdx.x >> 6, lane = threadIdx.x & 63;
  int row = blockIdx.x * 4 + wid;
#pragma unroll
  for (int hd = 0; hd < NHD; hd++) {
    float2 v  = ((const float2*)(h + ((size_t)hd * Nn + row) * Cc))[lane];
    float2 w1 = ((const float2*)(aw + hd * 2 * Cc))[lane];
    float2 w2 = ((const float2*)(aw + hd * 2 * Cc + Cc))[lane];
    float a = v.x * w1.x + v.y * w1.y;
    float b = v.x * w2.x + v.y * w2.y;
#pragma unroll
    for (int o = 32; o; o >>= 1) { a += __shfl_xor(a, o); b += __shfl_xor(b, o); }
    if (lane == 0) { ssrc[hd * Nn + row] = a; sdst[hd * Nn + row] = b; }
  }
}

// ---------------- kernel 3: per-row fused attention + residual + LN2 --------
// one block per row; both heads. Softmax support == mask (NEG underflows to 0).
// Phase C: 2 heads x 4 neighbor-groups x 32 channel-quads; float4 gathers,
// serial depth deg/4, 4x fewer VMEM instructions than scalar version.
__global__ __launch_bounds__(256) void k_attn(
    const float* __restrict__ adj, const float* __restrict__ x,
    const float* __restrict__ h, const float* __restrict__ ssrc,
    const float* __restrict__ sdst, const float* __restrict__ g2,
    const float* __restrict__ b2, float* __restrict__ att_out) {
  __shared__ __align__(16) int nbr[MAXDEG];          // later reused as attbuf[2][128]
  __shared__ __align__(16) float wts[NHD][MAXDEG];   // later reused as float4 part[256]
  __shared__ float red[8];
  __shared__ int cnt;
  const int t = threadIdx.x;
  const int r = blockIdx.x;
  if (t == 0) cnt = 0;
  __syncthreads();
  // phase A: scan adjacency row -> compact neighbor list (plus self-loop)
  const float4* arow = (const float4*)(adj + (size_t)r * Nn);
  for (int i = t; i < Nn / 4; i += 256) {
    float4 v = arow[i];
    int j = i * 4;
    if (v.x > 0.f || j + 0 == r) { int p = atomicAdd(&cnt, 1); if (p < MAXDEG) nbr[p] = j + 0; }
    if (v.y > 0.f || j + 1 == r) { int p = atomicAdd(&cnt, 1); if (p < MAXDEG) nbr[p] = j + 1; }
    if (v.z > 0.f || j + 2 == r) { int p = atomicAdd(&cnt, 1); if (p < MAXDEG) nbr[p] = j + 2; }
    if (v.w > 0.f || j + 3 == r) { int p = atomicAdd(&cnt, 1); if (p < MAXDEG) nbr[p] = j + 3; }
  }
  __syncthreads();
  const int deg = min(cnt, MAXDEG);
  const float s0 = ssrc[r], s1 = ssrc[Nn + r];
  // phase B1: logits + max
  float m0 = -3.0e38f, m1 = -3.0e38f;
  for (int k = t; k < deg; k += 256) {
    int j = nbr[k];
    float e0 = s0 + sdst[j];
    float e1 = s1 + sdst[Nn + j];
    e0 = (e0 > 0.f) ? e0 : 0.01f * e0;  // leaky_relu slope 0.01
    e1 = (e1 > 0.f) ? e1 : 0.01f * e1;
    wts[0][k] = e0; wts[1][k] = e1;
    m0 = fmaxf(m0, e0); m1 = fmaxf(m1, e1);
  }
  block_red2<true>(m0, m1, red);
  // phase B2: exp + sum
  float l0 = 0.f, l1 = 0.f;
  for (int k = t; k < deg; k += 256) {
    float w0 = __expf(wts[0][k] - m0); wts[0][k] = w0; l0 += w0;
    float w1 = __expf(wts[1][k] - m1); wts[1][k] = w1; l1 += w1;
  }
  block_red2<false>(l0, l1, red);
  // phase C: att[c] = (1/l) * sum_k w_k * h[head][nbr_k][c] + x[r][c]
  // thread decomposition: hd = t>>7 (head), g = (t>>5)&3 (neighbor group),
  // c4 = t&31 (channel quad). Wave = 2 neighbor rows x 512B -> 1KB/instr.
  {
    const int hd = t >> 7, g = (t >> 5) & 3, c4 = t & 31;
    const float* hp = h + (size_t)hd * Nn * Cc + c4 * 4;
    float4 a4 = make_float4(0.f, 0.f, 0.f, 0.f);
#pragma unroll 2
    for (int k = g; k < deg; k += 4) {
      float w = wts[hd][k];
      const float4 hv = *(const float4*)(hp + (size_t)nbr[k] * Cc);
      a4.x = fmaf(w, hv.x, a4.x);
      a4.y = fmaf(w, hv.y, a4.y);
      a4.z = fmaf(w, hv.z, a4.z);
      a4.w = fmaf(w, hv.w, a4.w);
    }
    __syncthreads();                       // wts/nbr no longer needed as-is
    float4* part = (float4*)&wts[0][0];    // 256 x float4 = 4KB scratch
    part[t] = a4;                          // index == hd*128 + g*32 + c4
    __syncthreads();
    float* attbuf = (float*)nbr;           // [2][128] floats = 1KB scratch
    if (t < 64) {
      const int hd2 = t >> 5, cb = t & 31;
      float4 p0 = part[hd2 * 128 + 0  + cb];
      float4 p1 = part[hd2 * 128 + 32 + cb];
      float4 p2 = part[hd2 * 128 + 64 + cb];
      float4 p3 = part[hd2 * 128 + 96 + cb];
      float sx_ = p0.x + p1.x + p2.x + p3.x;
      float sy_ = p0.y + p1.y + p2.y + p3.y;
      float sz_ = p0.z + p1.z + p2.z + p3.z;
      float sw_ = p0.w + p1.w + p2.w + p3.w;
      const float inv2 = 1.0f / (hd2 ? l1 : l0);
      const float4 xv = *(const float4*)(x + (size_t)r * Cc + cb * 4);
      float4 att4;
      att4.x = fmaf(sx_, inv2, xv.x);
      att4.y = fmaf(sy_, inv2, xv.y);
      att4.z = fmaf(sz_, inv2, xv.z);
      att4.w = fmaf(sw_, inv2, xv.w);
      ((float4*)attbuf)[hd2 * 32 + cb] = att4;
    }
    __syncthreads();
    // phase D: LN over the 128 channels of this head (2 waves per head)
    const int c = t & 127;
    float att = attbuf[(t >> 7) * 128 + c];
    float s = wave_red_sum(att);
    int wid = t >> 6;
    __syncthreads();
    if ((t & 63) == 0) red[wid] = s;
    __syncthreads();
    float mean = (red[(t >> 7) * 2] + red[(t >> 7) * 2 + 1]) * (1.0f / Cc);
    float d = att - mean;
    float q = wave_red_sum(d * d);
    __syncthreads();
    if ((t & 63) == 0) red[wid] = q;
    __syncthreads();
    float var = (red[(t >> 7) * 2] + red[(t >> 7) * 2 + 1]) * (1.0f / Cc);
    float rstd = rsqrtf(var + 1e-5f);
    att_out[((size_t)(t >> 7) * Nn + r) * Cc + c] = d * rstd * g2[c] + b2[c];
  }
}

extern "C" void kernel_launch(void* const* d_in, const int* in_sizes, int n_in,
                              void* d_out, int out_size, void* d_ws, size_t ws_size,
                              hipStream_t stream) {
  const float* x   = (const float*)d_in[0];
  const float* adj = (const float*)d_in[1];
  const float* ff0 = (const float*)d_in[2];
  const float* ff1 = (const float*)d_in[3];
  const float* aw  = (const float*)d_in[4];
  const float* g1  = (const float*)d_in[5];
  const float* b1  = (const float*)d_in[6];
  const float* g2  = (const float*)d_in[7];
  const float* b2  = (const float*)d_in[8];
  float* out = (float*)d_out;

  float* ws    = (float*)d_ws;
  float* xnorm = ws;                                  // Nn*Cc
  float* h     = xnorm + (size_t)Nn * Cc;             // 2*Nn*Cc
  float* ssrc  = h + (size_t)2 * Nn * Cc;             // 2*Nn
  float* sdst  = ssrc + 2 * Nn;                       // 2*Nn
  float* attn  = sdst + 2 * Nn;                       // 2*Nn*Cc
  // total ws use: ~15.8 MB (fp32)

  hipLaunchKernelGGL(k_ln, dim3(Nn / 4), dim3(256), 0, stream, x, g1, b1, xnorm);
  hipLaunchKernelGGL(k_gemm_ff0, dim3(Nn / 64, 2), dim3(256), 0, stream, xnorm, ff0, h);
  hipLaunchKernelGGL(k_attn_s, dim3(Nn / 4), dim3(256), 0, stream, h, aw, ssrc, sdst);
  hipLaunchKernelGGL(k_attn, dim3(Nn), dim3(256), 0, stream, adj, x, h, ssrc, sdst, g2, b2, attn);
  hipLaunchKernelGGL(k_gemm_ff1, dim3(Nn / 64), dim3(256), 0, stream, attn, ff1, out);
}

// Round 6
// 295.062 us; speedup vs baseline: 1.0543x; 1.0543x over previous
//
#include <hip/hip_runtime.h>
#include <math.h>

#define Nn 6144
#define Cc 128
#define NHD 2
#define MAXDEG 1024

// ---------------- warp/block reduction helpers ----------------
__device__ __forceinline__ float wave_red_sum(float v) {
#pragma unroll
  for (int o = 32; o; o >>= 1) v += __shfl_xor(v, o);
  return v;
}

template <bool IS_MAX>
__device__ __forceinline__ void block_red2(float& a, float& b, float* red) {
#pragma unroll
  for (int o = 32; o; o >>= 1) {
    float ta = __shfl_xor(a, o), tb = __shfl_xor(b, o);
    if (IS_MAX) { a = fmaxf(a, ta); b = fmaxf(b, tb); }
    else        { a += ta;          b += tb;          }
  }
  int wid = threadIdx.x >> 6;
  __syncthreads();
  if ((threadIdx.x & 63) == 0) { red[wid] = a; red[4 + wid] = b; }
  __syncthreads();
  if (IS_MAX) {
    a = fmaxf(fmaxf(red[0], red[1]), fmaxf(red[2], red[3]));
    b = fmaxf(fmaxf(red[4], red[5]), fmaxf(red[6], red[7]));
  } else {
    a = red[0] + red[1] + red[2] + red[3];
    b = red[4] + red[5] + red[6] + red[7];
  }
}

// ---------------- fused LN + FF0 GEMM + attn_s ------------------------------
// Per block: 32 rows, one head. LN in LDS (transposed [k][r]), then
// h = xn @ ff0[head]^T, then s_src/s_dst epilogue. grid (Nn/32, NHD).
__global__ __launch_bounds__(256) void k_ff0_fused(
    const float* __restrict__ x, const float* __restrict__ g1,
    const float* __restrict__ b1, const float* __restrict__ Bw,
    const float* __restrict__ aw, float* __restrict__ h,
    float* __restrict__ ssrc, float* __restrict__ sdst) {
  __shared__ float Axn[128][36];
  __shared__ float Bs[64][132];
  const int t = threadIdx.x;
  const int head = blockIdx.y;
  const int row0 = blockIdx.x * 32;
  const float* Bh = Bw + (size_t)head * Cc * Cc;

  // ---- stage + LN: 8 lanes per row, 16 cols per lane ----
  {
    const int row = t >> 3, seg = t & 7;
    const int cb = seg * 16;
    const float* xr = x + (size_t)(row0 + row) * Cc + cb;
    float v[16], gg[16], bb[16];
#pragma unroll
    for (int i = 0; i < 16; i += 4) {
      float4 t4 = *(const float4*)(xr + i);
      v[i] = t4.x; v[i + 1] = t4.y; v[i + 2] = t4.z; v[i + 3] = t4.w;
      float4 g4 = *(const float4*)(g1 + cb + i);
      gg[i] = g4.x; gg[i + 1] = g4.y; gg[i + 2] = g4.z; gg[i + 3] = g4.w;
      float4 b4 = *(const float4*)(b1 + cb + i);
      bb[i] = b4.x; bb[i + 1] = b4.y; bb[i + 2] = b4.z; bb[i + 3] = b4.w;
    }
    float s = 0.f;
#pragma unroll
    for (int i = 0; i < 16; i++) s += v[i];
    s += __shfl_xor(s, 1); s += __shfl_xor(s, 2); s += __shfl_xor(s, 4);
    float mean = s * (1.0f / 128.0f);
    float q = 0.f;
#pragma unroll
    for (int i = 0; i < 16; i++) { float d_ = v[i] - mean; q += d_ * d_; }
    q += __shfl_xor(q, 1); q += __shfl_xor(q, 2); q += __shfl_xor(q, 4);
    float rstd = rsqrtf(q * (1.0f / 128.0f) + 1e-5f);
#pragma unroll
    for (int i = 0; i < 16; i++)
      Axn[cb + i][row] = (v[i] - mean) * rstd * gg[i] + bb[i];
  }
  __syncthreads();

  // ---- GEMM: acc[4][4] ----
  const int tr = t & 7, tc = t >> 3;
  float acc[4][4];
#pragma unroll
  for (int i = 0; i < 4; i++)
#pragma unroll
    for (int j = 0; j < 4; j++) acc[i][j] = 0.f;

  for (int kt = 0; kt < Cc; kt += 64) {
    for (int i = t; i < 2048; i += 256) {
      int cc2 = i >> 4, k4 = i & 15;
      float4 v = *(const float4*)(Bh + (size_t)cc2 * Cc + kt + k4 * 4);
      Bs[k4 * 4 + 0][cc2] = v.x; Bs[k4 * 4 + 1][cc2] = v.y;
      Bs[k4 * 4 + 2][cc2] = v.z; Bs[k4 * 4 + 3][cc2] = v.w;
    }
    __syncthreads();
#pragma unroll
    for (int k = 0; k < 64; k++) {
      float4 a4 = *(const float4*)&Axn[kt + k][tr * 4];
      float4 b4 = *(const float4*)&Bs[k][tc * 4];
      float av[4] = {a4.x, a4.y, a4.z, a4.w};
      float bv[4] = {b4.x, b4.y, b4.z, b4.w};
#pragma unroll
      for (int i = 0; i < 4; i++)
#pragma unroll
        for (int j = 0; j < 4; j++) acc[i][j] = fmaf(av[i], bv[j], acc[i][j]);
    }
    __syncthreads();
  }

  // ---- store h + attn_s partials ----
  float psrc[4], pdst[4];
  {
    float4 w1 = *(const float4*)(aw + head * 2 * Cc + tc * 4);
    float4 w2 = *(const float4*)(aw + head * 2 * Cc + Cc + tc * 4);
#pragma unroll
    for (int i = 0; i < 4; i++) {
      float* op = h + ((size_t)head * Nn + row0 + tr * 4 + i) * Cc + tc * 4;
      *(float4*)op = make_float4(acc[i][0], acc[i][1], acc[i][2], acc[i][3]);
      psrc[i] = acc[i][0] * w1.x + acc[i][1] * w1.y + acc[i][2] * w1.z + acc[i][3] * w1.w;
      pdst[i] = acc[i][0] * w2.x + acc[i][1] * w2.y + acc[i][2] * w2.z + acc[i][3] * w2.w;
    }
  }
  float* epart = &Bs[0][0];  // [32 tc][32 row][2]
#pragma unroll
  for (int i = 0; i < 4; i++) {
    epart[((tc * 32) + (tr * 4 + i)) * 2 + 0] = psrc[i];
    epart[((tc * 32) + (tr * 4 + i)) * 2 + 1] = pdst[i];
  }
  __syncthreads();
  if (t < 64) {
    int row = t >> 1, s = t & 1;
    float v = 0.f;
#pragma unroll
    for (int g = 0; g < 32; g++) v += epart[(g * 32 + row) * 2 + s];
    (s ? sdst : ssrc)[head * Nn + row0 + row] = v;
  }
}

// ---------------- fused FF1 GEMM + head-combine, 32-row tiles ---------------
__global__ __launch_bounds__(256) void k_ff1_comb(const float* __restrict__ A,
                                                  const float* __restrict__ Bw,
                                                  float* __restrict__ out) {
  __shared__ float As[64][36];
  __shared__ float Bs[64][132];
  const int t = threadIdx.x;
  const int row0 = blockIdx.x * 32;
  const int tr = t & 7, tc = t >> 3;
  float sum[4][4];
#pragma unroll
  for (int i = 0; i < 4; i++)
#pragma unroll
    for (int j = 0; j < 4; j++) sum[i][j] = 0.f;

  for (int head = 0; head < NHD; head++) {
    const float* Ah = A + (size_t)head * Nn * Cc;
    const float* Bh = Bw + (size_t)head * Cc * Cc;
    float acc[4][4];
#pragma unroll
    for (int i = 0; i < 4; i++)
#pragma unroll
      for (int j = 0; j < 4; j++) acc[i][j] = 0.f;

    for (int kt = 0; kt < Cc; kt += 64) {
      __syncthreads();
      for (int i = t; i < 512; i += 256) {
        int rr = i >> 4, k4 = i & 15;
        float4 v = *(const float4*)(Ah + (size_t)(row0 + rr) * Cc + kt + k4 * 4);
        As[k4 * 4 + 0][rr] = v.x; As[k4 * 4 + 1][rr] = v.y;
        As[k4 * 4 + 2][rr] = v.z; As[k4 * 4 + 3][rr] = v.w;
      }
      for (int i = t; i < 2048; i += 256) {
        int cc2 = i >> 4, k4 = i & 15;
        float4 v = *(const float4*)(Bh + (size_t)cc2 * Cc + kt + k4 * 4);
        Bs[k4 * 4 + 0][cc2] = v.x; Bs[k4 * 4 + 1][cc2] = v.y;
        Bs[k4 * 4 + 2][cc2] = v.z; Bs[k4 * 4 + 3][cc2] = v.w;
      }
      __syncthreads();
#pragma unroll
      for (int k = 0; k < 64; k++) {
        float4 a4 = *(const float4*)&As[k][tr * 4];
        float4 b4 = *(const float4*)&Bs[k][tc * 4];
        float av[4] = {a4.x, a4.y, a4.z, a4.w};
        float bv[4] = {b4.x, b4.y, b4.z, b4.w};
#pragma unroll
        for (int i = 0; i < 4; i++)
#pragma unroll
          for (int j = 0; j < 4; j++) acc[i][j] = fmaf(av[i], bv[j], acc[i][j]);
      }
    }
#pragma unroll
    for (int i = 0; i < 4; i++)
#pragma unroll
      for (int j = 0; j < 4; j++) {
        float v = acc[i][j];
        v = (v > 0.f) ? v : (expf(v) - 1.f);
        sum[i][j] = fmaf(v, 0.5f, sum[i][j]);
      }
  }
#pragma unroll
  for (int i = 0; i < 4; i++) {
    float* op = out + (size_t)(row0 + tr * 4 + i) * Cc + tc * 4;
    *(float4*)op = make_float4(sum[i][0], sum[i][1], sum[i][2], sum[i][3]);
  }
}

// ---------------- kernel 3: per-row fused attention + residual + LN2 --------
// UNCHANGED from the round-4 verified version (isolates this round's delta).
__global__ __launch_bounds__(256) void k_attn(
    const float* __restrict__ adj, const float* __restrict__ x,
    const float* __restrict__ h, const float* __restrict__ ssrc,
    const float* __restrict__ sdst, const float* __restrict__ g2,
    const float* __restrict__ b2, float* __restrict__ att_out) {
  __shared__ __align__(16) int nbr[MAXDEG];
  __shared__ __align__(16) float wts[NHD][MAXDEG];
  __shared__ float red[8];
  __shared__ int cnt;
  const int t = threadIdx.x;
  const int r = blockIdx.x;
  if (t == 0) cnt = 0;
  __syncthreads();
  const float4* arow = (const float4*)(adj + (size_t)r * Nn);
  for (int i = t; i < Nn / 4; i += 256) {
    float4 v = arow[i];
    int j = i * 4;
    if (v.x > 0.f || j + 0 == r) { int p = atomicAdd(&cnt, 1); if (p < MAXDEG) nbr[p] = j + 0; }
    if (v.y > 0.f || j + 1 == r) { int p = atomicAdd(&cnt, 1); if (p < MAXDEG) nbr[p] = j + 1; }
    if (v.z > 0.f || j + 2 == r) { int p = atomicAdd(&cnt, 1); if (p < MAXDEG) nbr[p] = j + 2; }
    if (v.w > 0.f || j + 3 == r) { int p = atomicAdd(&cnt, 1); if (p < MAXDEG) nbr[p] = j + 3; }
  }
  __syncthreads();
  const int deg = min(cnt, MAXDEG);
  const float s0 = ssrc[r], s1 = ssrc[Nn + r];
  float m0 = -3.0e38f, m1 = -3.0e38f;
  for (int k = t; k < deg; k += 256) {
    int j = nbr[k];
    float e0 = s0 + sdst[j];
    float e1 = s1 + sdst[Nn + j];
    e0 = (e0 > 0.f) ? e0 : 0.01f * e0;
    e1 = (e1 > 0.f) ? e1 : 0.01f * e1;
    wts[0][k] = e0; wts[1][k] = e1;
    m0 = fmaxf(m0, e0); m1 = fmaxf(m1, e1);
  }
  block_red2<true>(m0, m1, red);
  float l0 = 0.f, l1 = 0.f;
  for (int k = t; k < deg; k += 256) {
    float w0 = __expf(wts[0][k] - m0); wts[0][k] = w0; l0 += w0;
    float w1 = __expf(wts[1][k] - m1); wts[1][k] = w1; l1 += w1;
  }
  block_red2<false>(l0, l1, red);
  {
    const int hd = t >> 7, g = (t >> 5) & 3, c4 = t & 31;
    const float* hp = h + (size_t)hd * Nn * Cc + c4 * 4;
    float4 a4 = make_float4(0.f, 0.f, 0.f, 0.f);
#pragma unroll 2
    for (int k = g; k < deg; k += 4) {
      float w = wts[hd][k];
      const float4 hv = *(const float4*)(hp + (size_t)nbr[k] * Cc);
      a4.x = fmaf(w, hv.x, a4.x);
      a4.y = fmaf(w, hv.y, a4.y);
      a4.z = fmaf(w, hv.z, a4.z);
      a4.w = fmaf(w, hv.w, a4.w);
    }
    __syncthreads();
    float4* part = (float4*)&wts[0][0];
    part[t] = a4;
    __syncthreads();
    float* attbuf = (float*)nbr;
    if (t < 64) {
      const int hd2 = t >> 5, cb = t & 31;
      float4 p0 = part[hd2 * 128 + 0  + cb];
      float4 p1 = part[hd2 * 128 + 32 + cb];
      float4 p2 = part[hd2 * 128 + 64 + cb];
      float4 p3 = part[hd2 * 128 + 96 + cb];
      float sx_ = p0.x + p1.x + p2.x + p3.x;
      float sy_ = p0.y + p1.y + p2.y + p3.y;
      float sz_ = p0.z + p1.z + p2.z + p3.z;
      float sw_ = p0.w + p1.w + p2.w + p3.w;
      const float inv2 = 1.0f / (hd2 ? l1 : l0);
      const float4 xv = *(const float4*)(x + (size_t)r * Cc + cb * 4);
      float4 att4;
      att4.x = fmaf(sx_, inv2, xv.x);
      att4.y = fmaf(sy_, inv2, xv.y);
      att4.z = fmaf(sz_, inv2, xv.z);
      att4.w = fmaf(sw_, inv2, xv.w);
      ((float4*)attbuf)[hd2 * 32 + cb] = att4;
    }
    __syncthreads();
    const int c = t & 127;
    float att = attbuf[(t >> 7) * 128 + c];
    float s = wave_red_sum(att);
    int wid = t >> 6;
    __syncthreads();
    if ((t & 63) == 0) red[wid] = s;
    __syncthreads();
    float mean = (red[(t >> 7) * 2] + red[(t >> 7) * 2 + 1]) * (1.0f / Cc);
    float d = att - mean;
    float q = wave_red_sum(d * d);
    __syncthreads();
    if ((t & 63) == 0) red[wid] = q;
    __syncthreads();
    float var = (red[(t >> 7) * 2] + red[(t >> 7) * 2 + 1]) * (1.0f / Cc);
    float rstd = rsqrtf(var + 1e-5f);
    att_out[((size_t)(t >> 7) * Nn + r) * Cc + c] = d * rstd * g2[c] + b2[c];
  }
}

extern "C" void kernel_launch(void* const* d_in, const int* in_sizes, int n_in,
                              void* d_out, int out_size, void* d_ws, size_t ws_size,
                              hipStream_t stream) {
  const float* x   = (const float*)d_in[0];
  const float* adj = (const float*)d_in[1];
  const float* ff0 = (const float*)d_in[2];
  const float* ff1 = (const float*)d_in[3];
  const float* aw  = (const float*)d_in[4];
  const float* g1  = (const float*)d_in[5];
  const float* b1  = (const float*)d_in[6];
  const float* g2  = (const float*)d_in[7];
  const float* b2  = (const float*)d_in[8];
  float* out = (float*)d_out;

  float* ws   = (float*)d_ws;
  float* h    = ws;                                  // 2*Nn*Cc
  float* ssrc = h + (size_t)2 * Nn * Cc;             // 2*Nn
  float* sdst = ssrc + 2 * Nn;                       // 2*Nn
  float* attn = sdst + 2 * Nn;                       // 2*Nn*Cc
  // total ws use: ~12.7 MB (fp32)

  hipLaunchKernelGGL(k_ff0_fused, dim3(Nn / 32, NHD), dim3(256), 0, stream,
                     x, g1, b1, ff0, aw, h, ssrc, sdst);
  hipLaunchKernelGGL(k_attn, dim3(Nn), dim3(256), 0, stream, adj, x, h, ssrc, sdst, g2, b2, attn);
  hipLaunchKernelGGL(k_ff1_comb, dim3(Nn / 32), dim3(256), 0, stream, attn, ff1, out);
}